// Round 10
// baseline (249.219 us; speedup 1.0000x reference)
//
#include <hip/hip_runtime.h>
#include <math.h>

typedef float float4u __attribute__((ext_vector_type(4), aligned(4)));

// ---------------------------------------------------------------------------
// VQCodebook forward, MI355X. B=256, D=128, K=8192, fp32.  3 kernels:
//  K1 conv1+ReLU+window-stats (2048 blocks, round-7 proven inner)
//     + Wcfg prework (288 blocks)
//  K2 vq_fused (512 blocks: 32 bg x 16 kc): pstat->S->z (redundant per kc,
//     bitwise-identical) -> ||z||^2 (kc==0) -> partial argmin with ||e||^2 inline
//  K3 argmin + losses + indices + decoder + expand (256 blocks)
// ---------------------------------------------------------------------------

// ------------------ K1: conv1 + relu + partial stats, and Wcfg pre-work ------------------
__global__ __launch_bounds__(256) void k_conv1_pre(
    const float* __restrict__ patch, const float* __restrict__ w1,
    const float* __restrict__ b1, const float* __restrict__ dw1,
    float* __restrict__ pstat, float* __restrict__ Wcfg)
{
    __shared__ __align__(16) float lds[2304];
    const int blk = blockIdx.x;
    const int tid = threadIdx.x;

    if (blk >= 2048) {   // ---- pre-work blocks: Wcfg ----
        const int gid = (blk - 2048) * 256 + tid;   // < 73728
        const int cfg = gid >> 13;
        const int o = (gid >> 7) & 63;
        const int i = gid & 127;
        const int cy = cfg / 3, cx = cfg % 3;
        const int ylo = (cy == 2) ? 1 : 0, yhi = (cy == 0) ? 1 : 2;
        const int xlo = (cx == 2) ? 1 : 0, xhi = (cx == 0) ? 1 : 2;
        const float* wp = dw1 + ((size_t)i * 64 + o) * 9;
        float s = 0.f;
        for (int ky = ylo; ky <= yhi; ++ky)
            for (int kx = xlo; kx <= xhi; ++kx)
                s += wp[ky * 3 + kx];
        Wcfg[gid] = s;
        return;
    }

    // ---- conv blocks: 8 output rows each ----
    const int b = blk >> 3, rg = blk & 7;
    const int y0 = rg * 8;
    const float* pb = patch + (size_t)b * 12288;
    // padded layout: [ic][r:10][p:72], input x at p=x+3, row r holds y=y0+r-1
    for (int i = tid; i < 2160; i += 256) {
        const int c = i / 720, rem = i - c * 720;
        const int r = rem / 72, p = rem - r * 72;
        const int y = y0 + r - 1, x = p - 3;
        float v = 0.f;
        if (y >= 0 && y < 64 && x >= 0 && x < 64)
            v = pb[(c << 12) + (y << 6) + x];
        lds[i] = v;
    }
    __syncthreads();

    const int ch = tid & 63, q = tid >> 6;   // q: 2 rows each
    float w[3][3][3];
#pragma unroll
    for (int ic = 0; ic < 3; ++ic)
#pragma unroll
        for (int ky = 0; ky < 3; ++ky)
#pragma unroll
            for (int kx = 0; kx < 3; ++kx)
                w[ic][ky][kx] = w1[((ch * 3 + ic) * 3 + ky) * 3 + kx];
    const float bias = b1[ch];

    float T = 0, r0s = 0, r63s = 0, c0s = 0, c63s = 0;
    float h00 = 0, h063 = 0, h630 = 0, h6363 = 0;

#pragma unroll
    for (int sub = 0; sub < 2; ++sub) {
        const int yl = q * 2 + sub;
        const bool isr0  = (rg == 0) && (yl == 0);
        const bool isr63 = (rg == 7) && (yl == 7);
        float cr[3][3][2];   // sliding carry: p = xc*4+2, xc*4+3
#pragma unroll
        for (int ic = 0; ic < 3; ++ic)
#pragma unroll
            for (int ky = 0; ky < 3; ++ky) {
                const float2 t2 = *(const float2*)&lds[(ic * 10 + yl + ky) * 72 + 2];
                cr[ic][ky][0] = t2.x; cr[ic][ky][1] = t2.y;
            }
#pragma unroll 4
        for (int xc = 0; xc < 16; ++xc) {
            float a0 = bias, a1 = bias, a2 = bias, a3 = bias;
#pragma unroll
            for (int ic = 0; ic < 3; ++ic)
#pragma unroll
                for (int ky = 0; ky < 3; ++ky) {
                    const float4 nw = *(const float4*)&lds[(ic * 10 + yl + ky) * 72 + xc * 4 + 4];
                    const float w0 = w[ic][ky][0], w1v = w[ic][ky][1], w2v = w[ic][ky][2];
                    a0 = fmaf(w0, cr[ic][ky][0], fmaf(w1v, cr[ic][ky][1], fmaf(w2v, nw.x, a0)));
                    a1 = fmaf(w0, cr[ic][ky][1], fmaf(w1v, nw.x, fmaf(w2v, nw.y, a1)));
                    a2 = fmaf(w0, nw.x, fmaf(w1v, nw.y, fmaf(w2v, nw.z, a2)));
                    a3 = fmaf(w0, nw.y, fmaf(w1v, nw.z, fmaf(w2v, nw.w, a3)));
                    cr[ic][ky][0] = nw.z; cr[ic][ky][1] = nw.w;
                }
            a0 = fmaxf(a0, 0.f); a1 = fmaxf(a1, 0.f);
            a2 = fmaxf(a2, 0.f); a3 = fmaxf(a3, 0.f);
            const float rs = (a0 + a1) + (a2 + a3);
            T += rs;
            if (isr0)  { r0s += rs;  if (xc == 0) h00 = a0;  if (xc == 15) h063 = a3; }
            if (isr63) { r63s += rs; if (xc == 0) h630 = a0; if (xc == 15) h6363 = a3; }
            if (xc == 0)  c0s += a0;
            if (xc == 15) c63s += a3;
        }
    }
    __syncthreads();   // reuse lds for reduction
    {
        const float st[9] = {T, r0s, r63s, c0s, c63s, h00, h063, h630, h6363};
#pragma unroll
        for (int s = 0; s < 9; ++s) lds[(s * 4 + q) * 64 + ch] = st[s];
    }
    __syncthreads();
    if (tid < 64) {
        float* pp = pstat + (size_t)blk * 576;
#pragma unroll
        for (int s = 0; s < 9; ++s)
            pp[s * 64 + tid] = (lds[(s * 4 + 0) * 64 + tid] + lds[(s * 4 + 1) * 64 + tid])
                             + (lds[(s * 4 + 2) * 64 + tid] + lds[(s * 4 + 3) * 64 + tid]);
    }
}

// ------------------ K2: fused z-compute + VQ partial argmin ------------------
// grid 512: bg = blk>>4 (8 batches), kc = blk&15 (512 codes)
__global__ __launch_bounds__(256) void k_vq(
    const float* __restrict__ pstat, const float* __restrict__ w2,
    const float* __restrict__ b2, const float* __restrict__ emb,
    float* __restrict__ zn2, float* __restrict__ pd2, int* __restrict__ pidx)
{
    __shared__ float fst8[8][576];                 // 18 KB
    __shared__ __align__(16) float Ssh8[8][576];   // 18 KB
    __shared__ __align__(16) float zsh[1024];      // 4 KB
    __shared__ float wd[8][4];
    __shared__ int   wi[8][4];
    const int tid = threadIdx.x;
    const int bg = blockIdx.x >> 4, kc = blockIdx.x & 15;
    const int b0 = bg * 8;

    // ---- phase 0a: reduce pstat (8 row-groups) for 8 batches ----
    for (int i = tid; i < 4608; i += 256) {
        const int bb = i / 576, j = i - bb * 576;
        const float* pp = pstat + ((size_t)(b0 + bb) * 8) * 576 + j;
        float s = 0.f;
#pragma unroll
        for (int g = 0; g < 8; ++g) s += pp[g * 576];
        fst8[bb][j] = s;
    }
    __syncthreads();

    // ---- phase 0b: S for 8 batches (512 tasks) ----
#pragma unroll
    for (int pp2 = 0; pp2 < 2; ++pp2) {
        const int t = tid + pp2 * 256;
        const int bb = t >> 6, ch = t & 63;
        const float* f = fst8[bb];
        const float Tt   = f[0 * 64 + ch], R0  = f[1 * 64 + ch], R63 = f[2 * 64 + ch];
        const float C0   = f[3 * 64 + ch], C63 = f[4 * 64 + ch];
        const float H00  = f[5 * 64 + ch], H063 = f[6 * 64 + ch];
        const float H630 = f[7 * 64 + ch], H6363 = f[8 * 64 + ch];
        float* Sp = &Ssh8[bb][ch * 9];
#pragma unroll
        for (int ky = 0; ky < 3; ++ky) {
            const float rex = (ky == 0) ? R63 : (ky == 2 ? R0 : 0.f);
#pragma unroll
            for (int kx = 0; kx < 3; ++kx) {
                const float cex = (kx == 0) ? C63 : (kx == 2 ? C0 : 0.f);
                float corner = 0.f;
                if (ky == 0 && kx == 0) corner = H6363;
                if (ky == 0 && kx == 2) corner = H630;
                if (ky == 2 && kx == 0) corner = H063;
                if (ky == 2 && kx == 2) corner = H00;
                Sp[ky * 3 + kx] = (Tt - rex - cex + corner) * (1.f / 4096.f);
            }
        }
    }
    __syncthreads();

    // ---- phase 0c: z GEMM — thread = (oc, half); 4 batches each, shared w2 row ----
    {
        const int oc = tid & 127, half = tid >> 7;
        const float4* Wv = (const float4*)(w2 + (size_t)oc * 576);
        const float bv = b2[oc];
#pragma unroll
        for (int jb = 0; jb < 4; ++jb) {
            const int bb = half * 4 + jb;
            const float4* Sv = (const float4*)Ssh8[bb];
            float acc = 0.f;
            for (int t = 0; t < 144; ++t) {
                const float4 w4 = Wv[t], s4 = Sv[t];
                acc = fmaf(w4.x, s4.x, acc);
                acc = fmaf(w4.y, s4.y, acc);
                acc = fmaf(w4.z, s4.z, acc);
                acc = fmaf(w4.w, s4.w, acc);
            }
            zsh[bb * 128 + oc] = bv + acc;
        }
    }
    __syncthreads();

    // ---- phase 0d: ||z||^2 per batch (kc==0 blocks only write) ----
    if (kc == 0) {
        const int bb = tid >> 5, l = tid & 31;
        float v = 0.f;
#pragma unroll
        for (int j = 0; j < 4; ++j) {
            const float zv = zsh[bb * 128 + j * 32 + l];
            v = fmaf(zv, zv, v);
        }
        v += __shfl_xor(v, 16); v += __shfl_xor(v, 8);
        v += __shfl_xor(v, 4);  v += __shfl_xor(v, 2); v += __shfl_xor(v, 1);
        if (l == 0) zn2[b0 + bb] = v;
    }

    // ---- phase 1: VQ partial argmin, ||e||^2 inline ----
    const int k0 = kc * 512 + tid, k1 = k0 + 256;
    const float4* e0 = (const float4*)(emb + (size_t)k0 * 128);
    const float4* e1 = (const float4*)(emb + (size_t)k1 * 128);
    const float4* zv = (const float4*)zsh;

    float acc0[8], acc1[8];
#pragma unroll
    for (int bb = 0; bb < 8; ++bb) { acc0[bb] = 0.f; acc1[bb] = 0.f; }
    float s0 = 0.f, s1 = 0.f;

    for (int t = 0; t < 32; ++t) {
        const float4 ea = e0[t], eb = e1[t];
        s0 = fmaf(ea.x, ea.x, fmaf(ea.y, ea.y, fmaf(ea.z, ea.z, fmaf(ea.w, ea.w, s0))));
        s1 = fmaf(eb.x, eb.x, fmaf(eb.y, eb.y, fmaf(eb.z, eb.z, fmaf(eb.w, eb.w, s1))));
#pragma unroll
        for (int bb = 0; bb < 8; ++bb) {
            const float4 zz = zv[bb * 32 + t];
            acc0[bb] = fmaf(zz.x, ea.x, fmaf(zz.y, ea.y, fmaf(zz.z, ea.z, fmaf(zz.w, ea.w, acc0[bb]))));
            acc1[bb] = fmaf(zz.x, eb.x, fmaf(zz.y, eb.y, fmaf(zz.z, eb.z, fmaf(zz.w, eb.w, acc1[bb]))));
        }
    }
    const int wv_ = tid >> 6, ln = tid & 63;
#pragma unroll
    for (int bb = 0; bb < 8; ++bb) {
        const float da = fmaf(-2.f, acc0[bb], s0);
        const float db = fmaf(-2.f, acc1[bb], s1);
        float d; int ix;
        if (da <= db) { d = da; ix = k0; } else { d = db; ix = k1; }
#pragma unroll
        for (int off = 32; off > 0; off >>= 1) {
            const float od = __shfl_xor(d, off);
            const int   oi = __shfl_xor(ix, off);
            if (od < d || (od == d && oi < ix)) { d = od; ix = oi; }
        }
        if (ln == 0) { wd[bb][wv_] = d; wi[bb][wv_] = ix; }
    }
    __syncthreads();
    if (tid < 8) {
        float d = wd[tid][0]; int ix = wi[tid][0];
#pragma unroll
        for (int wv2 = 1; wv2 < 4; ++wv2) {
            const float od = wd[tid][wv2]; const int oi = wi[tid][wv2];
            if (od < d || (od == d && oi < ix)) { d = od; ix = oi; }
        }
        pd2[(b0 + tid) * 16 + kc] = d;
        pidx[(b0 + tid) * 16 + kc] = ix;
    }
}

// ------------------ K3: argmin + losses + indices + full decoder + expand ------------------
__global__ __launch_bounds__(256) void k_decode(
    const float* __restrict__ emb, const float* __restrict__ zn2,
    const float* __restrict__ pd2, const int* __restrict__ pidx,
    const float* __restrict__ Wcfg, const float* __restrict__ db1,
    const float* __restrict__ dw2, const float* __restrict__ db2,
    const float* __restrict__ dw3, const float* __restrict__ db3,
    float* __restrict__ out)
{
    __shared__ __align__(16) float zsh[128];
    __shared__ float d1e[64][10];
    __shared__ float d2e[64][26];
    __shared__ float o3[3 * 49];
    __shared__ float dw3sh[1728];
    __shared__ float redl[256];
    __shared__ int bsel;

    const int b = blockIdx.x, tid = threadIdx.x;

    // ---- phase 0: final argmin, batch 'tid' per thread ----
    float dmin = pd2[tid * 16]; int bi = pidx[tid * 16];
    for (int j = 1; j < 16; ++j) {
        const float d = pd2[tid * 16 + j]; const int ix = pidx[tid * 16 + j];
        if (d < dmin || (d == dmin && ix < bi)) { dmin = d; bi = ix; }
    }
    if (tid == b) bsel = bi;
    redl[tid] = dmin + zn2[tid];
    __syncthreads();

    if (b == 0) out[3145730 + tid] = (float)bi;
    if (tid < 128) {
        redl[tid] += redl[tid + 128];
        zsh[tid] = emb[(size_t)bsel * 128 + tid];
    }
    for (int id = tid; id < 1728; id += 256) dw3sh[id] = dw3[id];
    if (tid < 64) { d1e[tid][9] = 0.f; d2e[tid][25] = 0.f; }
    __syncthreads();

    if (tid < 64) {
        float v = redl[tid] + redl[tid + 64];
        v += __shfl_xor(v, 32); v += __shfl_xor(v, 16); v += __shfl_xor(v, 8);
        v += __shfl_xor(v, 4);  v += __shfl_xor(v, 2);  v += __shfl_xor(v, 1);
        if (tid == 0 && b == 0) {
            const float L = v * (1.f / 32768.f);
            out[3145728] = L;
            out[3145729] = L;
        }
    }

    // ---- stage 1: d1e[o][cfg] = relu(db1 + Wcfg[cfg][o][:] . zq) ----
    for (int id = tid; id < 576; id += 256) {
        const int o = id / 9, cfg = id - o * 9;
        const float4* wv = (const float4*)(Wcfg + ((size_t)cfg * 64 + o) * 128);
        const float4* zv = (const float4*)zsh;
        float acc = db1[o];
        for (int t = 0; t < 32; ++t) {
            const float4 w4 = wv[t], z4 = zv[t];
            acc = fmaf(w4.x, z4.x, acc);
            acc = fmaf(w4.y, z4.y, acc);
            acc = fmaf(w4.z, z4.z, acc);
            acc = fmaf(w4.w, z4.w, acc);
        }
        d1e[o][cfg] = fmaxf(acc, 0.f);
    }
    __syncthreads();

    // ---- stage 2: 25 cfgs; thread = (o, i-quarter); shfl reduce ----
    {
        const int TY5[5][3] = {{-1,0,1},{0,1,1},{1,1,1},{1,1,2},{1,2,-1}};
        const int o = tid >> 2, isub = tid & 3;
        float acc[25];
#pragma unroll
        for (int cc = 0; cc < 25; ++cc) acc[cc] = 0.f;
        for (int ii = 0; ii < 16; ++ii) {
            const int i = isub + ii * 4;
            float d1v[10];
#pragma unroll
            for (int t = 0; t < 9; ++t) d1v[t] = d1e[i][t];
            d1v[9] = 0.f;
            const float* wp = dw2 + ((size_t)i * 64 + o) * 9;
            const float4u w03 = *(const float4u*)wp;
            const float4u w47 = *(const float4u*)(wp + 4);
            const float w8v = wp[8];
            const float w9[9] = {w03.x, w03.y, w03.z, w03.w, w47.x, w47.y, w47.z, w47.w, w8v};
#pragma unroll
            for (int cy = 0; cy < 5; ++cy) {
#pragma unroll
                for (int ky = 0; ky < 3; ++ky) {
                    const int ty = TY5[cy][ky];
                    if (ty < 0) continue;
#pragma unroll
                    for (int cx = 0; cx < 5; ++cx) {
#pragma unroll
                        for (int kx = 0; kx < 3; ++kx) {
                            const int tx = TY5[cx][kx];
                            if (tx < 0) continue;
                            acc[cy * 5 + cx] = fmaf(w9[(2 - ky) * 3 + (2 - kx)],
                                                    d1v[ty * 3 + tx], acc[cy * 5 + cx]);
                        }
                    }
                }
            }
        }
#pragma unroll
        for (int cc = 0; cc < 25; ++cc) {
            float v = acc[cc];
            v += __shfl_xor(v, 1);
            v += __shfl_xor(v, 2);
            if (isub == 0) d2e[o][cc] = fmaxf(v + db2[o], 0.f);
        }
    }
    __syncthreads();

    // ---- stage 3: 49 cfgs x 3 channels ----
    if (tid < 147) {
        const int TY7[7][3] = {{-1,0,1},{0,1,2},{1,2,2},{2,2,2},{2,2,3},{2,3,4},{3,4,-1}};
        const int c3 = tid / 49, cc = tid % 49, cy = cc / 7, cx = cc % 7;
        float acc = db3[c3];
        for (int i = 0; i < 64; ++i) {
            const float* wp = &dw3sh[(i * 3 + c3) * 9];
#pragma unroll
            for (int ky = 0; ky < 3; ++ky) {
                const int ty = TY7[cy][ky];
#pragma unroll
                for (int kx = 0; kx < 3; ++kx) {
                    const int tx = TY7[cx][kx];
                    const int t = (ty < 0 || tx < 0) ? 25 : ty * 5 + tx;
                    acc = fmaf(wp[(2 - ky) * 3 + (2 - kx)], d2e[i][t], acc);
                }
            }
        }
        o3[c3 * 49 + cc] = tanhf(acc);
    }
    __syncthreads();

    // ---- expand + float4 write ----
    float4* ob = (float4*)(out + (size_t)b * 12288);
    for (int id = tid; id < 3072; id += 256) {
        const int base = id * 4;
        const int c = base >> 12, rem = base & 4095, y = rem >> 6, x0 = rem & 63;
        const int ry = (y <= 3) ? y : (y >= 60 ? y - 57 : 3);
        const float* row = &o3[c * 49 + ry * 7];
        float4 v;
        int x;
        x = x0 + 0; v.x = row[(x <= 3) ? x : (x >= 60 ? x - 57 : 3)];
        x = x0 + 1; v.y = row[(x <= 3) ? x : (x >= 60 ? x - 57 : 3)];
        x = x0 + 2; v.z = row[(x <= 3) ? x : (x >= 60 ? x - 57 : 3)];
        x = x0 + 3; v.w = row[(x <= 3) ? x : (x >= 60 ? x - 57 : 3)];
        ob[id] = v;
    }
}

// ---------------------------------------------------------------------------
extern "C" void kernel_launch(void* const* d_in, const int* in_sizes, int n_in,
                              void* d_out, int out_size, void* d_ws, size_t ws_size,
                              hipStream_t stream)
{
    const float* patch  = (const float*)d_in[0];
    const float* enc_w1 = (const float*)d_in[1];
    const float* enc_b1 = (const float*)d_in[2];
    const float* enc_w2 = (const float*)d_in[3];
    const float* enc_b2 = (const float*)d_in[4];
    const float* emb    = (const float*)d_in[5];
    const float* dec_w1 = (const float*)d_in[6];
    const float* dec_b1 = (const float*)d_in[7];
    const float* dec_w2 = (const float*)d_in[8];
    const float* dec_b2 = (const float*)d_in[9];
    const float* dec_w3 = (const float*)d_in[10];
    const float* dec_b3 = (const float*)d_in[11];

    float* out = (float*)d_out;
    float* ws  = (float*)d_ws;

    float* pstat = ws;                     // 2048*576 = 1179648
    float* zn2   = ws + 1179648;           // 256
    float* pd2   = ws + 1179904;           // 4096
    int*   pidx  = (int*)(ws + 1184000);   // 4096
    float* Wcfg  = ws + 1188096;           // 73728

    k_conv1_pre<<<dim3(2336), dim3(256), 0, stream>>>(patch, enc_w1, enc_b1, dec_w1,
                                                      pstat, Wcfg);
    k_vq<<<dim3(512), dim3(256), 0, stream>>>(pstat, enc_w2, enc_b2, emb,
                                              zn2, pd2, pidx);
    k_decode<<<dim3(256), dim3(256), 0, stream>>>(emb, zn2, pd2, pidx, Wcfg, dec_b1,
                                                  dec_w2, dec_b2, dec_w3, dec_b3, out);
}